// Round 11
// baseline (60.082 us; speedup 1.0000x reference)
//
#include <hip/hip_runtime.h>
#include <math.h>

#define H 256
#define EPS 1e-4f
#define LSTR 584   // per-wave LDS stride in floats: 584 mod 32 = 8 -> waves
                   // staggered across banks (576 would alias all 8 waves)

// ---- DPP helpers (gfx9/CDNA), bound_ctrl:0 (0-fill invalid lanes) ----
template <int CTRL>
__device__ __forceinline__ float dpp0(float x) {
    return __int_as_float(
        __builtin_amdgcn_update_dpp(0, __float_as_int(x), CTRL, 0xf, 0xf, true));
}
__device__ __forceinline__ float rdlane(float x, int l) {
    return __int_as_float(__builtin_amdgcn_readlane(__float_as_int(x), l));
}
__device__ __forceinline__ float frcp_fast(float v) { return __builtin_amdgcn_rcpf(v); }
__device__ __forceinline__ float frcp_nr(float v) {
    float r = __builtin_amdgcn_rcpf(v);
    return fmaf(r, fmaf(-v, r, 1.0f), r);
}
// full-wave sum of two values, result uniform
__device__ __forceinline__ void wave_red_sum2(float& a, float& b) {
    a += dpp0<0x111>(a);  b += dpp0<0x111>(b);
    a += dpp0<0x112>(a);  b += dpp0<0x112>(b);
    a += dpp0<0x114>(a);  b += dpp0<0x114>(b);
    a += dpp0<0x118>(a);  b += dpp0<0x118>(b);
    a += dpp0<0x142>(a);  b += dpp0<0x142>(b);
    a += dpp0<0x143>(a);  b += dpp0<0x143>(b);
    a = rdlane(a, 63);
    b = rdlane(b, 63);
}

// Schur step k with scalar lookahead. KF1=(k+1)&3, KF2=(k+2)&3 literals;
// LN1=(k+1)>>2, LN2=(k+2)>>2 (SGPR). Readlanes touch only previous-step vectors.
#define STEP(KF1, KF2, LN1, LN2) do {                                   \
    float g  = -sF * isB;                                               \
    float sE = fmaf(g, sF, sB);              /* B_{k+1}[k+1] */         \
    isB = frcp_fast(sE);                                                \
    float mu = sR * isB;                                                \
    float rlF2 = rdlane(F[KF2], (LN2));      /* F_k[k+2] */             \
    float rlB1 = rdlane(Bv[KF1], (LN1));     /* B_k[k+1] */             \
    float rlR2 = rdlane(Rv[KF2], (LN2));     /* R_k[k+2] */             \
    sF = fmaf(g, rlB1, rlF2);                /* F_{k+1}[k+2] */         \
    float tB2 = fmaf(g, rlF2, rlB1);         /* B_{k+1}[k+2] */         \
    sR = fmaf(-mu, tB2, rlR2);               /* R_{k+1}[k+2] */         \
    sB = sE;                                                            \
    float sb0 = dpp0<0x138>(Bv[3]);          /* wave_shr:1 */           \
    float sr0 = dpp0<0x138>(rav[3]);                                    \
    float nB0 = fmaf(g, F[0], sb0);                                     \
    float nB1 = fmaf(g, F[1], Bv[0]);                                   \
    float nB2 = fmaf(g, F[2], Bv[1]);                                   \
    float nB3 = fmaf(g, F[3], Bv[2]);                                   \
    float nF0 = fmaf(g, sb0,  F[0]);                                    \
    float nF1 = fmaf(g, Bv[0], F[1]);                                   \
    float nF2 = fmaf(g, Bv[1], F[2]);                                   \
    float nF3 = fmaf(g, Bv[2], F[3]);                                   \
    float nr0 = fmaf(g, av[0], sr0);                                    \
    float nr1 = fmaf(g, av[1], rav[0]);                                 \
    float nr2 = fmaf(g, av[2], rav[1]);                                 \
    float nr3 = fmaf(g, av[3], rav[2]);                                 \
    float na0 = fmaf(g, sr0,   av[0]);                                  \
    float na1 = fmaf(g, rav[0], av[1]);                                 \
    float na2 = fmaf(g, rav[1], av[2]);                                 \
    float na3 = fmaf(g, rav[2], av[3]);                                 \
    xv[0] = fmaf(mu, nr0, xv[0]);  Rv[0] = fmaf(-mu, nB0, Rv[0]);       \
    xv[1] = fmaf(mu, nr1, xv[1]);  Rv[1] = fmaf(-mu, nB1, Rv[1]);       \
    xv[2] = fmaf(mu, nr2, xv[2]);  Rv[2] = fmaf(-mu, nB2, Rv[2]);       \
    xv[3] = fmaf(mu, nr3, xv[3]);  Rv[3] = fmaf(-mu, nB3, Rv[3]);       \
    Bv[0]=nB0; Bv[1]=nB1; Bv[2]=nB2; Bv[3]=nB3;                         \
    F[0]=nF0; F[1]=nF1; F[2]=nF2; F[3]=nF3;                             \
    av[0]=na0; av[1]=na1; av[2]=na2; av[3]=na3;                         \
    rav[0]=nr0; rav[1]=nr1; rav[2]=nr2; rav[3]=nr3;                     \
} while (0)

// 8 waves per block, one batch per wave; 64 blocks -> 1 block/CU on 64 CUs
// -> 2 waves/SIMD. Co-resident waves share the SIMD's issue slots (a lone
// wave issues ~1 VALU/4cy; two waves alternate to ~1/2cy each-pair).
// __launch_bounds__(512, 2): min 2 waves/EU -> VGPR cap 256 (R10's implicit
// cap of 32 caused scratch spilling and a 2x regression).
__global__ __launch_bounds__(512, 2) void awloss_batch(
        const float* __restrict__ recon,
        const float* __restrict__ target,
        float* __restrict__ losses) {
    const int lane = threadIdx.x & 63;
    const int wid  = threadIdx.x >> 6;
    const int b    = blockIdx.x * 8 + wid;
    const bool l0  = (lane == 0);

    __shared__ __align__(16) float tgtp_s[8][LSTR];  // per-wave: t zero-padded
    __shared__ __align__(16) float recp_s[8][LSTR];  // per-wave: rec at [127..382]
    float* tgtp = tgtp_s[wid];
    float* recp = recp_s[wid];

    const float4 tv4 = ((const float4*)(target + b * H))[lane];
    const float4 rv4 = ((const float4*)(recon  + b * H))[lane];

    #pragma unroll
    for (int c = 0; c < 9; ++c) { tgtp[c*64+lane] = 0.f; recp[c*64+lane] = 0.f; }
    __syncthreads();
    *(float4*)&tgtp[4*lane] = tv4;
    recp[127 + 4*lane + 0] = rv4.x;
    recp[127 + 4*lane + 1] = rv4.y;
    recp[127 + 4*lane + 2] = rv4.z;
    recp[127 + 4*lane + 3] = rv4.w;
    __syncthreads();

    // --- correlation r[d], b[d], lane-major d = 4*lane+c; b128 sliding window ---
    float racc[4] = {0.f,0.f,0.f,0.f}, bacc[4] = {0.f,0.f,0.f,0.f};
    float4 W0t = *(const float4*)&tgtp[4*lane];
    float4 W0r = *(const float4*)&recp[4*lane];
    for (int m0 = 0; m0 < 256; m0 += 4) {
        float4 W1t = *(const float4*)&tgtp[m0 + 4 + 4*lane];
        float4 W1r = *(const float4*)&recp[m0 + 4 + 4*lane];
        float t0s = rdlane(W0t.x, 0);
        float t1s = rdlane(W0t.y, 0);
        float t2s = rdlane(W0t.z, 0);
        float t3s = rdlane(W0t.w, 0);
        racc[0] = fmaf(t0s, W0t.x, racc[0]); bacc[0] = fmaf(t0s, W0r.x, bacc[0]);
        racc[1] = fmaf(t0s, W0t.y, racc[1]); bacc[1] = fmaf(t0s, W0r.y, bacc[1]);
        racc[2] = fmaf(t0s, W0t.z, racc[2]); bacc[2] = fmaf(t0s, W0r.z, bacc[2]);
        racc[3] = fmaf(t0s, W0t.w, racc[3]); bacc[3] = fmaf(t0s, W0r.w, bacc[3]);
        racc[0] = fmaf(t1s, W0t.y, racc[0]); bacc[0] = fmaf(t1s, W0r.y, bacc[0]);
        racc[1] = fmaf(t1s, W0t.z, racc[1]); bacc[1] = fmaf(t1s, W0r.z, bacc[1]);
        racc[2] = fmaf(t1s, W0t.w, racc[2]); bacc[2] = fmaf(t1s, W0r.w, bacc[2]);
        racc[3] = fmaf(t1s, W1t.x, racc[3]); bacc[3] = fmaf(t1s, W1r.x, bacc[3]);
        racc[0] = fmaf(t2s, W0t.z, racc[0]); bacc[0] = fmaf(t2s, W0r.z, bacc[0]);
        racc[1] = fmaf(t2s, W0t.w, racc[1]); bacc[1] = fmaf(t2s, W0r.w, bacc[1]);
        racc[2] = fmaf(t2s, W1t.x, racc[2]); bacc[2] = fmaf(t2s, W1r.x, bacc[2]);
        racc[3] = fmaf(t2s, W1t.y, racc[3]); bacc[3] = fmaf(t2s, W1r.y, bacc[3]);
        racc[0] = fmaf(t3s, W0t.w, racc[0]); bacc[0] = fmaf(t3s, W0r.w, bacc[0]);
        racc[1] = fmaf(t3s, W1t.x, racc[1]); bacc[1] = fmaf(t3s, W1r.x, bacc[1]);
        racc[2] = fmaf(t3s, W1t.y, racc[2]); bacc[2] = fmaf(t3s, W1r.y, bacc[2]);
        racc[3] = fmaf(t3s, W1t.z, racc[3]); bacc[3] = fmaf(t3s, W1r.z, bacc[3]);
        W0t = W1t; W0r = W1r;
    }

    // --- normalize; init Schur state directly in lane-major registers ---
    float t0v = rdlane(racc[0], 0) + EPS;
    float it0 = frcp_nr(t0v);
    float F[4], Bv[4], av[4], rav[4], xv[4], Rv[4];
    #pragma unroll
    for (int c = 0; c < 4; ++c) {
        float rh = racc[c] * it0;
        if (c == 0) rh = l0 ? 1.0f : rh;   // rho[0] = (r0+eps)/t0 = 1 exactly
        F[c] = rh; Bv[c] = rh;
    }
    float bb0 = rdlane(bacc[0], 0) * it0;
    #pragma unroll
    for (int c = 0; c < 4; ++c) {
        float bvv = bacc[c] * it0;
        Rv[c] = fmaf(-bb0, F[c], bvv);     // R_0 = bb - bb0*rho
        xv[c] = 0.f; av[c] = 0.f; rav[c] = 0.f;
    }
    if (l0) { xv[0] = bb0; av[0] = 1.0f; rav[0] = 1.0f; }

    float sF  = rdlane(F[1], 0);           // F_0[1] = rho[1]
    float sB  = 1.0f, isB = 1.0f;
    float sR  = rdlane(Rv[1], 0);          // R_0[1]

    // --- 255 Schur steps, x4 unrolled for literal register indices ---
    for (int t = 0; t < 63; ++t) {
        STEP(1, 2, t, t);                  // k = 4t
        STEP(2, 3, t, t);                  // k = 4t+1
        STEP(3, 0, t, t + 1);              // k = 4t+2
        STEP(0, 1, t + 1, t + 1);          // k = 4t+3
    }
    STEP(1, 2, 63, 63);                    // k = 252
    STEP(2, 3, 63, 63);                    // k = 253
    {   // k = 254: only mu and the x update matter
        float g  = -sF * isB;
        float sE = fmaf(g, sF, sB);
        float mu = sR * frcp_fast(sE);
        float sr0 = dpp0<0x138>(rav[3]);
        xv[0] = fmaf(mu, fmaf(g, av[0], sr0),    xv[0]);
        xv[1] = fmaf(mu, fmaf(g, av[1], rav[0]), xv[1]);
        xv[2] = fmaf(mu, fmaf(g, av[2], rav[1]), xv[2]);
        xv[3] = fmaf(mu, fmaf(g, av[3], rav[2]), xv[3]);
    }

    // --- loss: 0.5*sqrt(sum((T*v)^2)/sum(v^2)), elements e = 4*lane+c ---
    float sT = 0.f, sV = 0.f;
    const float dxg = 20.0f / 255.0f;
    #pragma unroll
    for (int c = 0; c < 4; ++c) {
        float v  = xv[c];
        float u  = -10.0f + dxg * (float)(4*lane + c) + 0.5f * dxg;
        float Ti = 1.0f - expf(-0.5f * u * u);   // T normalizers == 1.0f in f32
        float tw = Ti * v;
        sT += tw * tw;
        sV += v * v;
    }
    wave_red_sum2(sT, sV);
    if (l0) losses[b] = 0.5f * sqrtf(sT / sV);
}

// deterministic final reduction of 512 per-batch losses
__global__ __launch_bounds__(64) void awloss_reduce(
        const float* __restrict__ losses, float* __restrict__ out) {
    int lane = threadIdx.x;
    float s = 0.f;
    #pragma unroll
    for (int c = 0; c < 8; ++c) s += losses[c * 64 + lane];
    float d = 0.f;
    wave_red_sum2(s, d);
    if (lane == 0) out[0] = s;
}

extern "C" void kernel_launch(void* const* d_in, const int* in_sizes, int n_in,
                              void* d_out, int out_size, void* d_ws, size_t ws_size,
                              hipStream_t stream) {
    const float* recon  = (const float*)d_in[0];
    const float* target = (const float*)d_in[1];
    float* losses = (float*)d_ws;   // 512 floats
    float* out    = (float*)d_out;

    awloss_batch<<<64, 512, 0, stream>>>(recon, target, losses);
    awloss_reduce<<<1, 64, 0, stream>>>(losses, out);
}

// Round 12
// 27.239 us; speedup vs baseline: 2.2057x; 2.2057x over previous
//
#include <hip/hip_runtime.h>
#include <math.h>

#define H 256
#define EPS 1e-4f

// ---- DPP helpers (gfx9/CDNA), bound_ctrl:0 (0-fill invalid lanes) ----
template <int CTRL>
__device__ __forceinline__ float dpp0(float x) {
    return __int_as_float(
        __builtin_amdgcn_update_dpp(0, __float_as_int(x), CTRL, 0xf, 0xf, true));
}
__device__ __forceinline__ float rdlane(float x, int l) {
    return __int_as_float(__builtin_amdgcn_readlane(__float_as_int(x), l));
}
__device__ __forceinline__ float frcp_fast(float v) { return __builtin_amdgcn_rcpf(v); }
__device__ __forceinline__ float frcp_nr(float v) {
    float r = __builtin_amdgcn_rcpf(v);
    return fmaf(r, fmaf(-v, r, 1.0f), r);
}
// full-wave sum of two values, result uniform
__device__ __forceinline__ void wave_red_sum2(float& a, float& b) {
    a += dpp0<0x111>(a);  b += dpp0<0x111>(b);
    a += dpp0<0x112>(a);  b += dpp0<0x112>(b);
    a += dpp0<0x114>(a);  b += dpp0<0x114>(b);
    a += dpp0<0x118>(a);  b += dpp0<0x118>(b);
    a += dpp0<0x142>(a);  b += dpp0<0x142>(b);
    a += dpp0<0x143>(a);  b += dpp0<0x143>(b);
    a = rdlane(a, 63);
    b = rdlane(b, 63);
}

// Support-packed Schur step k -> k+1.
// P = a|F (a on elements <=k, F on >=k+1), Q = ra|B (ra <=k-1 .. B >=k),
// X = x|-R (x <=k, -R >=k+1).  Same update form on both halves:
//   P' = P + g*sh1(Q);  Q' = sh1(Q) + g*P;  X' = X + mu*Q'.
// Boundary: Q'[k+1] = sB+g*sF = sE auto-corrects; P'[k+1] <- g and
// X'[k+1] <- mu fixed with one v_cmp + 2 cndmask (static reg index KF1).
// Scalar lookahead (reads only pre-update vectors): identical to proven R5.
#define STEP(KF1, KF2, LN1, LN2) do {                                   \
    float g  = -sF * isB;                                               \
    float sE = fmaf(g, sF, sB);              /* B_{k+1}[k+1] */         \
    isB = frcp_fast(sE);                                                \
    float mu = -sRt * isB;                                              \
    float rlF2 = rdlane(P[KF2], (LN2));      /* F_k[k+2]  */            \
    float rlB1 = rdlane(Q[KF1], (LN1));      /* B_k[k+1]  */            \
    float rlR2 = rdlane(X[KF2], (LN2));      /* -R_k[k+2] */            \
    sF  = fmaf(g, rlB1, rlF2);               /* F_{k+1}[k+2] */         \
    float tB2 = fmaf(g, rlF2, rlB1);         /* B_{k+1}[k+2] */         \
    sRt = fmaf(mu, tB2, rlR2);               /* -R_{k+1}[k+2] */        \
    sB  = sE;                                                           \
    float shq0 = dpp0<0x138>(Q[3]);          /* wave_shr:1 */           \
    float nQ0 = fmaf(g, P[0], shq0);                                    \
    float nQ1 = fmaf(g, P[1], Q[0]);                                    \
    float nQ2 = fmaf(g, P[2], Q[1]);                                    \
    float nQ3 = fmaf(g, P[3], Q[2]);                                    \
    float nP0 = fmaf(g, shq0, P[0]);                                    \
    float nP1 = fmaf(g, Q[0],  P[1]);                                   \
    float nP2 = fmaf(g, Q[1],  P[2]);                                   \
    float nP3 = fmaf(g, Q[2],  P[3]);                                   \
    X[0] = fmaf(mu, nQ0, X[0]);                                         \
    X[1] = fmaf(mu, nQ1, X[1]);                                         \
    X[2] = fmaf(mu, nQ2, X[2]);                                         \
    X[3] = fmaf(mu, nQ3, X[3]);                                         \
    bool bm = (lane == (LN1));               /* element k+1's lane */   \
    P[0]=nP0; P[1]=nP1; P[2]=nP2; P[3]=nP3;                             \
    Q[0]=nQ0; Q[1]=nQ1; Q[2]=nQ2; Q[3]=nQ3;                             \
    P[KF1] = bm ? g  : P[KF1];                                          \
    X[KF1] = bm ? mu : X[KF1];                                          \
} while (0)

// One wave per batch. Schur solve of symmetric Toeplitz A v = b, with the
// three packed sequences P, Q, X (halved vector work vs the 6-array form).
__global__ __launch_bounds__(64) void awloss_batch(
        const float* __restrict__ recon,
        const float* __restrict__ target,
        float* __restrict__ losses) {
    const int b    = blockIdx.x;
    const int lane = threadIdx.x;
    const bool l0  = (lane == 0);

    __shared__ __align__(16) float tgtp[576];   // t padded with zeros
    __shared__ __align__(16) float recp[576];   // rec at [127..382], zeros else

    const float4 tv4 = ((const float4*)(target + b * H))[lane];
    const float4 rv4 = ((const float4*)(recon  + b * H))[lane];

    #pragma unroll
    for (int c = 0; c < 9; ++c) { tgtp[c*64+lane] = 0.f; recp[c*64+lane] = 0.f; }
    __syncthreads();
    *(float4*)&tgtp[4*lane] = tv4;
    recp[127 + 4*lane + 0] = rv4.x;
    recp[127 + 4*lane + 1] = rv4.y;
    recp[127 + 4*lane + 2] = rv4.z;
    recp[127 + 4*lane + 3] = rv4.w;
    __syncthreads();

    // --- correlation r[d], b[d], lane-major d = 4*lane+c; b128 sliding window ---
    float racc[4] = {0.f,0.f,0.f,0.f}, bacc[4] = {0.f,0.f,0.f,0.f};
    float4 W0t = *(const float4*)&tgtp[4*lane];
    float4 W0r = *(const float4*)&recp[4*lane];
    for (int m0 = 0; m0 < 256; m0 += 4) {
        float4 W1t = *(const float4*)&tgtp[m0 + 4 + 4*lane];
        float4 W1r = *(const float4*)&recp[m0 + 4 + 4*lane];
        float t0s = rdlane(W0t.x, 0);
        float t1s = rdlane(W0t.y, 0);
        float t2s = rdlane(W0t.z, 0);
        float t3s = rdlane(W0t.w, 0);
        racc[0] = fmaf(t0s, W0t.x, racc[0]); bacc[0] = fmaf(t0s, W0r.x, bacc[0]);
        racc[1] = fmaf(t0s, W0t.y, racc[1]); bacc[1] = fmaf(t0s, W0r.y, bacc[1]);
        racc[2] = fmaf(t0s, W0t.z, racc[2]); bacc[2] = fmaf(t0s, W0r.z, bacc[2]);
        racc[3] = fmaf(t0s, W0t.w, racc[3]); bacc[3] = fmaf(t0s, W0r.w, bacc[3]);
        racc[0] = fmaf(t1s, W0t.y, racc[0]); bacc[0] = fmaf(t1s, W0r.y, bacc[0]);
        racc[1] = fmaf(t1s, W0t.z, racc[1]); bacc[1] = fmaf(t1s, W0r.z, bacc[1]);
        racc[2] = fmaf(t1s, W0t.w, racc[2]); bacc[2] = fmaf(t1s, W0r.w, bacc[2]);
        racc[3] = fmaf(t1s, W1t.x, racc[3]); bacc[3] = fmaf(t1s, W1r.x, bacc[3]);
        racc[0] = fmaf(t2s, W0t.z, racc[0]); bacc[0] = fmaf(t2s, W0r.z, bacc[0]);
        racc[1] = fmaf(t2s, W0t.w, racc[1]); bacc[1] = fmaf(t2s, W0r.w, bacc[1]);
        racc[2] = fmaf(t2s, W1t.x, racc[2]); bacc[2] = fmaf(t2s, W1r.x, bacc[2]);
        racc[3] = fmaf(t2s, W1t.y, racc[3]); bacc[3] = fmaf(t2s, W1r.y, bacc[3]);
        racc[0] = fmaf(t3s, W0t.w, racc[0]); bacc[0] = fmaf(t3s, W0r.w, bacc[0]);
        racc[1] = fmaf(t3s, W1t.x, racc[1]); bacc[1] = fmaf(t3s, W1r.x, bacc[1]);
        racc[2] = fmaf(t3s, W1t.y, racc[2]); bacc[2] = fmaf(t3s, W1r.y, bacc[2]);
        racc[3] = fmaf(t3s, W1t.z, racc[3]); bacc[3] = fmaf(t3s, W1r.z, bacc[3]);
        W0t = W1t; W0r = W1r;
    }

    // --- normalize; init packed state (lane-major e = 4*lane+c) ---
    float t0v = rdlane(racc[0], 0) + EPS;
    float it0 = frcp_nr(t0v);
    float P[4], Q[4], X[4];
    #pragma unroll
    for (int c = 0; c < 4; ++c) {
        float rh = racc[c] * it0;
        if (c == 0) rh = l0 ? 1.0f : rh;   // rho[0] = 1; also a_0[0]=1, B_0[0]=1
        P[c] = rh; Q[c] = rh;              // P = a|F = rho; Q = ra|B = rho
    }
    float bb0 = rdlane(bacc[0], 0) * it0;
    #pragma unroll
    for (int c = 0; c < 4; ++c) {
        float bvv = bacc[c] * it0;
        X[c] = fmaf(bb0, P[c], -bvv);      // -R_0 = bb0*rho - bb
    }
    if (l0) X[0] = bb0;                    // x_0[0] = bb0

    float sF  = rdlane(P[1], 0);           // F_0[1] = rho[1]
    float sB  = 1.0f, isB = 1.0f;
    float sRt = rdlane(X[1], 0);           // -R_0[1]

    // --- 255 Schur steps, x4 unrolled for literal register indices ---
    for (int t = 0; t < 63; ++t) {
        STEP(1, 2, t, t);                  // k = 4t
        STEP(2, 3, t, t);                  // k = 4t+1
        STEP(3, 0, t, t + 1);              // k = 4t+2
        STEP(0, 1, t + 1, t + 1);          // k = 4t+3
    }
    STEP(1, 2, 63, 63);                    // k = 252
    STEP(2, 3, 63, 63);                    // k = 253
    {   // k = 254: only mu and the X update matter (element 255 <- mu)
        float g  = -sF * isB;
        float sE = fmaf(g, sF, sB);
        float mu = -sRt * frcp_fast(sE);
        float shq0 = dpp0<0x138>(Q[3]);
        float nQ0 = fmaf(g, P[0], shq0);
        float nQ1 = fmaf(g, P[1], Q[0]);
        float nQ2 = fmaf(g, P[2], Q[1]);
        float nQ3 = fmaf(g, P[3], Q[2]);
        X[0] = fmaf(mu, nQ0, X[0]);
        X[1] = fmaf(mu, nQ1, X[1]);
        X[2] = fmaf(mu, nQ2, X[2]);
        X[3] = fmaf(mu, nQ3, X[3]);
        X[3] = (lane == 63) ? mu : X[3];
    }

    // --- loss: 0.5*sqrt(sum((T*v)^2)/sum(v^2)), elements e = 4*lane+c ---
    float sT = 0.f, sV = 0.f;
    const float dxg = 20.0f / 255.0f;
    #pragma unroll
    for (int c = 0; c < 4; ++c) {
        float v  = X[c];
        float u  = -10.0f + dxg * (float)(4*lane + c) + 0.5f * dxg;
        float Ti = 1.0f - expf(-0.5f * u * u);   // T normalizers == 1.0f in f32
        float tw = Ti * v;
        sT += tw * tw;
        sV += v * v;
    }
    wave_red_sum2(sT, sV);
    if (l0) losses[b] = 0.5f * sqrtf(sT / sV);
}

// deterministic final reduction of 512 per-batch losses
__global__ __launch_bounds__(64) void awloss_reduce(
        const float* __restrict__ losses, float* __restrict__ out) {
    int lane = threadIdx.x;
    float s = 0.f;
    #pragma unroll
    for (int c = 0; c < 8; ++c) s += losses[c * 64 + lane];
    float d = 0.f;
    wave_red_sum2(s, d);
    if (lane == 0) out[0] = s;
}

extern "C" void kernel_launch(void* const* d_in, const int* in_sizes, int n_in,
                              void* d_out, int out_size, void* d_ws, size_t ws_size,
                              hipStream_t stream) {
    const float* recon  = (const float*)d_in[0];
    const float* target = (const float*)d_in[1];
    float* losses = (float*)d_ws;   // 512 floats
    float* out    = (float*)d_out;

    awloss_batch<<<512, 64, 0, stream>>>(recon, target, losses);
    awloss_reduce<<<1, 64, 0, stream>>>(losses, out);
}